// Round 20
// baseline (237.788 us; speedup 1.0000x reference)
//
#include <hip/hip_runtime.h>
#include <hip/hip_bf16.h>
#include <math.h>

constexpr int B_ = 4;
constexpr int C_ = 256;
constexpr int GH = 40, GW = 40, GP = 1600;   // refine-level grid
constexpr int KDIM = C_ * 9;                  // 2304
constexpr int MT = B_ * GP;                   // 6400
constexpr int NGEMM = 400;                    // gemm blocks in fused launch

typedef __attribute__((ext_vector_type(8))) short short8b;   // 8 bf16 (4 VGPRs)
typedef __attribute__((ext_vector_type(4))) float f32x4;

__device__ inline ushort f2b(float f) {
    __hip_bfloat16 h = __float2bfloat16(f);
    return *reinterpret_cast<ushort*>(&h);
}
__device__ inline float b2f(ushort u) {
    unsigned v = (unsigned)u << 16;
    return *reinterpret_cast<float*>(&v);
}

// ---- Stage 1: ori_fe (PIXEL-MAJOR [b][pix][c]) via LDS transpose ----------------
__global__ __launch_bounds__(256) void fe_kernel(const float* __restrict__ x0,
                                                 const float* __restrict__ x1,
                                                 const float* __restrict__ x2,
                                                 const float* __restrict__ x3,
                                                 const float* __restrict__ x4,
                                                 float* __restrict__ fe_pm) {
    __shared__ float tile[64][65];
    int pix0 = blockIdx.x * 64;
    int c0 = blockIdx.y * 64;
    int b = blockIdx.z;
    int lx = threadIdx.x & 63;   // pixel lane
    int ly = threadIdx.x >> 6;   // 4 rows

    int pix = pix0 + lx;
    int h = pix / GW, w = pix - (pix / GW) * GW;
#pragma unroll
    for (int r = 0; r < 64; r += 4) {
        int c = c0 + ly + r;
        size_t bc = (size_t)b * C_ + c;
        const float* p0 = x0 + bc * 25600;
        float m0 = -INFINITY;
#pragma unroll
        for (int dy = 0; dy < 4; ++dy)
#pragma unroll
            for (int dx = 0; dx < 4; ++dx)
                m0 = fmaxf(m0, p0[(4 * h + dy) * 160 + 4 * w + dx]);
        const float* p1 = x1 + bc * 6400;
        float m1 = -INFINITY;
#pragma unroll
        for (int dy = 0; dy < 2; ++dy)
#pragma unroll
            for (int dx = 0; dx < 2; ++dx)
                m1 = fmaxf(m1, p1[(2 * h + dy) * 80 + 2 * w + dx]);
        float v2 = x2[bc * GP + pix];
        float v3 = x3[bc * 400 + (h / 2) * 20 + (w / 2)];
        float v4 = x4[bc * 100 + (h / 4) * 10 + (w / 4)];
        tile[ly + r][lx] = (m0 + m1 + v2 + v3 + v4) * 0.2f;
    }
    __syncthreads();
#pragma unroll
    for (int r = 0; r < 64; r += 4) {
        int p = ly + r;
        fe_pm[((size_t)b * GP + pix0 + p) * C_ + c0 + lx] = tile[lx][p];
    }
}

// ---- weight permute+convert (both weights in one launch) ------------------------
__global__ void wcvt_kernel(const float* __restrict__ wA, const float* __restrict__ wB,
                            ushort* __restrict__ oA, ushort* __restrict__ oB) {
    const float* w = blockIdx.y ? wB : wA;
    ushort* out = blockIdx.y ? oB : oA;
    int idx = blockIdx.x * 256 + threadIdx.x;   // 256*2304
    int o = idx / KDIM;
    int rem = idx - o * KDIM;
    int c = rem / 9, t = rem - c * 9;
    out[(size_t)o * KDIM + t * 256 + c] = f2b(w[idx]);
}

// ---- im2col (3x3 pad1 on fe_pm) -> A1[b*1600+pix][t*256+c] bf16 -----------------
__global__ void im2col_kernel(const float* __restrict__ fe_pm, ushort* __restrict__ A1) {
    int pix = blockIdx.x % GP, b = blockIdx.x / GP;
    int c = threadIdx.x;
    const float* fb = fe_pm + (size_t)b * GP * C_;
    ushort* dst = A1 + (size_t)blockIdx.x * KDIM;
    int h = pix / GW, w = pix - (pix / GW) * GW;
#pragma unroll
    for (int t = 0; t < 9; ++t) {
        int y = h + t / 3 - 1, x = w + t % 3 - 1;
        float v = (y >= 0 && y < GH && x >= 0 && x < GW) ? fb[(size_t)(y * GW + x) * C_ + c]
                                                         : 0.f;
        dst[t * 256 + c] = f2b(v);
    }
}

// ---- bilinear sampling (fe_pm) -> S[b*1600+pix][t*256+c] bf16 -------------------
__global__ void sample_kernel(const float* __restrict__ fe_pm, const float* __restrict__ pts,
                              ushort* __restrict__ S) {
    int pix = blockIdx.x % GP, b = blockIdx.x / GP;
    int c = threadIdx.x;
    const float* fb = fe_pm + (size_t)b * GP * C_;
    const float* pb = pts + (size_t)b * 18 * GP + pix;
    ushort* dst = S + (size_t)blockIdx.x * KDIM;
    int h = pix / GW, w = pix - (pix / GW) * GW;
#pragma unroll
    for (int t = 0; t < 9; ++t) {
        float py = (float)h + pb[(2 * t) * GP];
        float px = (float)w + pb[(2 * t + 1) * GP];
        float y0f = floorf(py), x0f = floorf(px);
        int y0 = (int)y0f, x0 = (int)x0f;
        float wy1 = py - y0f, wx1 = px - x0f;
        float wy0 = 1.f - wy1, wx0 = 1.f - wx1;
        auto tap = [&](int yy, int xx) -> float {
            return (yy >= 0 && yy < GH && xx >= 0 && xx < GW)
                       ? fb[(size_t)(yy * GW + xx) * C_ + c]
                       : 0.f;
        };
        float v = tap(y0, x0) * wy0 * wx0 + tap(y0, x0 + 1) * wy0 * wx1 +
                  tap(y0 + 1, x0) * wy1 * wx0 + tap(y0 + 1, x0 + 1) * wy1 * wx1;
        dst[t * 256 + c] = f2b(v);
    }
}

// ---- per-level tables ------------------------------------------------------------
__device__ constexpr int L_S[5] = {160, 80, 40, 20, 10};
__device__ constexpr int L_NPX[5] = {102400, 25600, 6400, 1600, 400};
__device__ constexpr int YK_START[5] = {0, 400, 500, 525, 532};      // 534 blocks total
__device__ constexpr int FC_START[5] = {0, 1600, 2000, 2100, 2125};  // 2132 blocks total
__device__ constexpr size_t L_YBASE[5] = {0, 7372800, 9216000, 9676800, 9792000};
__device__ constexpr size_t L_OUT[5] = {0, 26214400, 32768000, 34406400, 34816000};

__device__ inline int lvl_of(int bx, const int* start) {
    return (bx >= start[4]) ? 4 : (bx >= start[3]) ? 3 : (bx >= start[2]) ? 2
           : (bx >= start[1]) ? 1 : 0;
}

// ---- yk device body: y[g][conv*9+t][bp] = sum_{c in grp} w[c,t]*x[c,bp] ----------
__device__ inline void yk_body(int bx, int g, const float* x0, const float* x1,
                               const float* x2, const float* x3, const float* x4,
                               const float* w_red1, const float* w_red2,
                               ushort* y_all) {
    int lvl = lvl_of(bx, YK_START);
    const float* x = lvl == 0 ? x0 : lvl == 1 ? x1 : lvl == 2 ? x2 : lvl == 3 ? x3 : x4;
    int s = L_S[lvl];
    int npx = L_NPX[lvl];
    int bp = (bx - YK_START[lvl]) * 256 + threadIdx.x;
    if (bp >= npx) return;
    int ss_ = s * s;
    int b = bp / ss_;
    int p = bp - b * ss_;
    const float* xg = x + ((size_t)b * C_ + g * 64) * ss_ + p;
    const float* w1g = w_red1 + (size_t)lvl * KDIM + g * 64 * 9;
    const float* w2g = w_red2 + (size_t)lvl * KDIM + g * 64 * 9;
    float a1[9] = {}, a2[9] = {};
#pragma unroll 4
    for (int ci = 0; ci < 64; ++ci) {
        float v = xg[(size_t)ci * ss_];
#pragma unroll
        for (int t = 0; t < 9; ++t) {
            a1[t] += w1g[ci * 9 + t] * v;
            a2[t] += w2g[ci * 9 + t] * v;
        }
    }
    ushort* yb = y_all + L_YBASE[lvl] + bp;
#pragma unroll
    for (int t = 0; t < 9; ++t) {
        yb[(size_t)(g * 18 + t) * npx] = f2b(a1[t]);
        yb[(size_t)(g * 18 + 9 + t) * npx] = f2b(a2[t]);
    }
}

// ---- fused: bf16 MFMA GEMM (blocks 0..399) + yk rider (blocks 400+) -------------
// GEMM: r15 structure — 64x64 tile, BK=64, pure-copy staging, depth-2 X/Y, dbuf.
// Rider: 2 channel-groups (g_base..g_base+1) x 534 level-blocks of yk work.
__global__ __launch_bounds__(256) void gemm_yk(const ushort* __restrict__ A,
                                               const ushort* __restrict__ Bw,
                                               const float* __restrict__ bias,
                                               float* __restrict__ Cout,
                                               const float* __restrict__ x0,
                                               const float* __restrict__ x1,
                                               const float* __restrict__ x2,
                                               const float* __restrict__ x3,
                                               const float* __restrict__ x4,
                                               const float* __restrict__ w_red1,
                                               const float* __restrict__ w_red2,
                                               ushort* __restrict__ y_all,
                                               int g_base) {
    __shared__ ushort As[2][64 * 64];
    __shared__ ushort Bs[2][64 * 64];

    if (blockIdx.x >= NGEMM) {   // ---- yk rider path (no LDS, no barriers) ----
        int bxx = blockIdx.x - NGEMM;
        int g = g_base + bxx / 534;
        yk_body(bxx % 534, g, x0, x1, x2, x3, x4, w_red1, w_red2, y_all);
        return;
    }

    // ---- GEMM path ----
    int tid = threadIdx.x;
    int lane = tid & 63;
    int wid = tid >> 6;
    int wm = wid >> 1, wn = wid & 1;
    int m0 = (blockIdx.x >> 2) * 64;
    int n0 = (blockIdx.x & 3) * 64;

    int sr = tid >> 3;                  // staging row 0..31 (and +32)
    int ss = tid & 7;                   // logical 16B slot 0..7
    int wsl = (ss ^ (sr & 7)) * 8;      // swizzled short offset within row
    const ushort* gA0 = A + (size_t)(m0 + sr) * KDIM + ss * 8;
    const ushort* gA1 = A + (size_t)(m0 + sr + 32) * KDIM + ss * 8;
    const ushort* gB0 = Bw + (size_t)(n0 + sr) * KDIM + ss * 8;
    const ushort* gB1 = Bw + (size_t)(n0 + sr + 32) * KDIM + ss * 8;

    f32x4 acc[2][2];
#pragma unroll
    for (int i = 0; i < 2; ++i)
#pragma unroll
        for (int j = 0; j < 2; ++j) acc[i][j] = (f32x4){0.f, 0.f, 0.f, 0.f};

    short8b xA0, xA1, xB0, xB1;   // register set X
    short8b yA0, yA1, yB0, yB1;   // register set Y

    auto loadX = [&]() {
        xA0 = *(const short8b*)gA0; xA1 = *(const short8b*)gA1;
        xB0 = *(const short8b*)gB0; xB1 = *(const short8b*)gB1;
        gA0 += 64; gA1 += 64; gB0 += 64; gB1 += 64;
    };
    auto loadY = [&]() {
        yA0 = *(const short8b*)gA0; yA1 = *(const short8b*)gA1;
        yB0 = *(const short8b*)gB0; yB1 = *(const short8b*)gB1;
        gA0 += 64; gA1 += 64; gB0 += 64; gB1 += 64;
    };
    auto writeL = [&](int buf, short8b a0, short8b a1, short8b b0, short8b b1) {
        *(short8b*)(As[buf] + sr * 64 + wsl) = a0;
        *(short8b*)(As[buf] + (sr + 32) * 64 + wsl) = a1;
        *(short8b*)(Bs[buf] + sr * 64 + wsl) = b0;
        *(short8b*)(Bs[buf] + (sr + 32) * 64 + wsl) = b1;
    };
    auto compute = [&](int cur) {
#pragma unroll
        for (int kq = 0; kq < 2; ++kq) {
            int k16 = kq * 4 + (lane >> 4);
            short8b af[2], bfr[2];
#pragma unroll
            for (int i = 0; i < 2; ++i) {
                int rA = wm * 32 + i * 16 + (lane & 15);
                af[i] = *(const short8b*)(As[cur] + rA * 64 + ((k16 ^ (rA & 7)) * 8));
                int rB = wn * 32 + i * 16 + (lane & 15);
                bfr[i] = *(const short8b*)(Bs[cur] + rB * 64 + ((k16 ^ (rB & 7)) * 8));
            }
#pragma unroll
            for (int in = 0; in < 2; ++in)
#pragma unroll
                for (int im = 0; im < 2; ++im)
                    acc[in][im] = __builtin_amdgcn_mfma_f32_16x16x32_bf16(
                        bfr[in], af[im], acc[in][im], 0, 0, 0);
        }
    };

    constexpr int NCH = KDIM / 64;   // 36 chunks (even)
    loadX();                          // chunk 0
    loadY();                          // chunk 1
    writeL(0, xA0, xA1, xB0, xB1);
    __syncthreads();

    for (int kc = 0; kc < NCH; kc += 2) {
        if (kc + 2 < NCH) loadX();
        compute(0);
        writeL(1, yA0, yA1, yB0, yB1);
        __syncthreads();
        if (kc + 3 < NCH) loadY();
        compute(1);
        if (kc + 2 < NCH) writeL(0, xA0, xA1, xB0, xB1);
        __syncthreads();
    }

    int b = m0 / GP;
    int pix0 = m0 - b * GP;     // 1600 % 64 == 0 -> tile never crosses batch
    float* Cb = Cout + (size_t)b * C_ * GP;
#pragma unroll
    for (int in = 0; in < 2; ++in) {
#pragma unroll
        for (int r = 0; r < 4; ++r) {
            int n = n0 + wn * 32 + in * 16 + (lane >> 4) * 4 + r;
            float bv = bias ? bias[n] : 0.f;
#pragma unroll
            for (int im = 0; im < 2; ++im) {
                int m = pix0 + wm * 32 + im * 16 + (lane & 15);
                Cb[(size_t)n * GP + m] = fmaxf(acc[in][im][r] + bv, 0.f);
            }
        }
    }
}

// ---- pts = conv1x1(p1, w_pts_out) + b -------------------------------------------
__global__ void pts_kernel(const float* __restrict__ p1, const float* __restrict__ wpo,
                           const float* __restrict__ bpo, float* __restrict__ pts) {
    int idx = blockIdx.x * 256 + threadIdx.x;   // over B*18*1600
    int pix = idx % GP;
    int p = (idx / GP) % 18;
    int b = idx / (GP * 18);
    const float* pb = p1 + (size_t)b * C_ * GP + pix;
    const float* wp = wpo + p * C_;
    float s = bpo[p];
    for (int c = 0; c < C_; ++c) s += pb[(size_t)c * GP] * wp[c];
    pts[idx] = s;
}

// ---- att pass 2 + combine (ALL levels) -------------------------------------------
__global__ __launch_bounds__(256) void fincomb_all(const float* __restrict__ x0,
                                                   const float* __restrict__ x1,
                                                   const float* __restrict__ x2,
                                                   const float* __restrict__ x3,
                                                   const float* __restrict__ x4,
                                                   const ushort* __restrict__ y_all,
                                                   const float* __restrict__ b_red1,
                                                   const float* __restrict__ b_red2,
                                                   const float* __restrict__ bsf,
                                                   float* __restrict__ out) {
    __shared__ float red[2][4][64];
    __shared__ float amap_s[64];
    int bx = blockIdx.x;
    int lvl = lvl_of(bx, FC_START);
    const float* x = lvl == 0 ? x0 : lvl == 1 ? x1 : lvl == 2 ? x2 : lvl == 3 ? x3 : x4;
    int s = L_S[lvl];
    int npx = L_NPX[lvl];
    const ushort* y = y_all + L_YBASE[lvl];
    float* out_l = out + L_OUT[lvl];
    int lane = threadIdx.x & 63;
    int grp = threadIdx.x >> 6;
    int pix_g = (bx - FC_START[lvl]) * 64 + lane;
    bool valid = pix_g < npx;
    int pg = valid ? pix_g : 0;
    int ss_ = s * s;
    int b = pg / ss_;
    int pix = pg - b * ss_;
    int h = pix / s, w = pix - h * s;
    const ushort* yg = y + (size_t)grp * 18 * npx;
    float s1 = 0.f, s2 = 0.f;
#pragma unroll
    for (int t = 0; t < 9; ++t) {
        int dy = t / 3 - 1, dx = t % 3 - 1;
        int hy = h + dy, wx = w + dx;
        if (hy >= 0 && hy < s && wx >= 0 && wx < s) {
            int qq = pg + dy * s + dx;
            s1 += b2f(yg[(size_t)t * npx + qq]);
            s2 += b2f(yg[(size_t)(9 + t) * npx + qq]);
        }
    }
    red[0][grp][lane] = s1;
    red[1][grp][lane] = s2;
    __syncthreads();
    if (grp == 0) {
        float t1 = red[0][0][lane] + red[0][1][lane] + red[0][2][lane] + red[0][3][lane];
        float t2 = red[1][0][lane] + red[1][1][lane] + red[1][2][lane] + red[1][3][lane];
        t1 = tanhf(fmaxf(t1 + b_red1[lvl], 0.f));
        t2 = tanhf(fmaxf(t2 + b_red2[lvl], 0.f));
        amap_s[lane] = t1 + t2;
    }
    __syncthreads();
    if (!valid) return;
    float av = amap_s[lane];
    int gh = h * GH / s, gw = w * GW / s;
    const float* bb = bsf + (size_t)b * C_ * GP + gh * GW + gw;
    const float* xp = x + ((size_t)b * C_ + grp * 64) * ss_ + pix;
    float* op = out_l + ((size_t)b * C_ + grp * 64) * ss_ + pix;
#pragma unroll 4
    for (int ci = 0; ci < 64; ++ci) {
        int c = grp * 64 + ci;
        op[(size_t)ci * ss_] = xp[(size_t)ci * ss_] + bb[(size_t)c * GP] * av;
    }
}

extern "C" void kernel_launch(void* const* d_in, const int* in_sizes, int n_in,
                              void* d_out, int out_size, void* d_ws, size_t ws_size,
                              hipStream_t stream) {
    const float* x[5];
    for (int i = 0; i < 5; ++i) x[i] = (const float*)d_in[i];
    const float* w_red1 = (const float*)d_in[5];
    const float* b_red1 = (const float*)d_in[6];
    const float* w_red2 = (const float*)d_in[7];
    const float* b_red2 = (const float*)d_in[8];
    const float* w_pts_conv = (const float*)d_in[9];
    const float* b_pts_conv = (const float*)d_in[10];
    const float* w_pts_out = (const float*)d_in[11];
    const float* b_pts_out = (const float*)d_in[12];
    const float* w_refine = (const float*)d_in[13];
    float* out = (float*)d_out;

    // workspace layout
    float* ws = (float*)d_ws;
    float* fe_pm = ws;                     // 1,638,400 f32  [b][pix][c]
    float* p1 = fe_pm + 1638400;           // 1,638,400 f32
    float* pts = p1 + 1638400;             //   115,200 f32
    float* bsf = pts + 115200;             // 1,638,400 f32
    ushort* y_all = (ushort*)(bsf + 1638400);      // 9,820,800 bf16 (all levels)
    ushort* AS_buf = y_all + 9820800;              // 14,745,600 bf16 (A1, then S)
    ushort* Wb1 = AS_buf + (size_t)MT * KDIM;      //   589,824 bf16
    ushort* Wb2 = Wb1 + (size_t)C_ * KDIM;         //   589,824 bf16
    // total ~71.4 MB

    fe_kernel<<<dim3(25, 4, B_), 256, 0, stream>>>(x[0], x[1], x[2], x[3], x[4], fe_pm);
    wcvt_kernel<<<dim3(2304, 2), 256, 0, stream>>>(w_pts_conv, w_refine, Wb1, Wb2);
    im2col_kernel<<<MT, 256, 0, stream>>>(fe_pm, AS_buf);
    gemm_yk<<<NGEMM + 1068, 256, 0, stream>>>(AS_buf, Wb1, b_pts_conv, p1,
                                              x[0], x[1], x[2], x[3], x[4],
                                              w_red1, w_red2, y_all, 0);
    pts_kernel<<<450, 256, 0, stream>>>(p1, w_pts_out, b_pts_out, pts);
    sample_kernel<<<MT, 256, 0, stream>>>(fe_pm, pts, AS_buf);   // overwrites A1
    gemm_yk<<<NGEMM + 1068, 256, 0, stream>>>(AS_buf, Wb2, nullptr, bsf,
                                              x[0], x[1], x[2], x[3], x[4],
                                              w_red1, w_red2, y_all, 2);
    fincomb_all<<<2132, 256, 0, stream>>>(x[0], x[1], x[2], x[3], x[4], y_all,
                                          b_red1, b_red2, bsf, out);
}

// Round 21
// 227.289 us; speedup vs baseline: 1.0462x; 1.0462x over previous
//
#include <hip/hip_runtime.h>
#include <hip/hip_bf16.h>
#include <math.h>

constexpr int B_ = 4;
constexpr int C_ = 256;
constexpr int GH = 40, GW = 40, GP = 1600;   // refine-level grid
constexpr int KDIM = C_ * 9;                  // 2304
constexpr int MT = B_ * GP;                   // 6400

typedef __attribute__((ext_vector_type(8))) short short8b;   // 8 bf16 (4 VGPRs)
typedef __attribute__((ext_vector_type(4))) float f32x4;

__device__ inline ushort f2b(float f) {
    __hip_bfloat16 h = __float2bfloat16(f);
    return *reinterpret_cast<ushort*>(&h);
}
__device__ inline float b2f(ushort u) {
    unsigned v = (unsigned)u << 16;
    return *reinterpret_cast<float*>(&v);
}

// ---- Stage 1: ori_fe (PIXEL-MAJOR [b][pix][c]) via LDS transpose ----------------
__global__ __launch_bounds__(256) void fe_kernel(const float* __restrict__ x0,
                                                 const float* __restrict__ x1,
                                                 const float* __restrict__ x2,
                                                 const float* __restrict__ x3,
                                                 const float* __restrict__ x4,
                                                 float* __restrict__ fe_pm) {
    __shared__ float tile[64][65];
    int pix0 = blockIdx.x * 64;
    int c0 = blockIdx.y * 64;
    int b = blockIdx.z;
    int lx = threadIdx.x & 63;   // pixel lane
    int ly = threadIdx.x >> 6;   // 4 rows

    int pix = pix0 + lx;
    int h = pix / GW, w = pix - (pix / GW) * GW;
#pragma unroll
    for (int r = 0; r < 64; r += 4) {
        int c = c0 + ly + r;
        size_t bc = (size_t)b * C_ + c;
        const float* p0 = x0 + bc * 25600;
        float m0 = -INFINITY;
#pragma unroll
        for (int dy = 0; dy < 4; ++dy)
#pragma unroll
            for (int dx = 0; dx < 4; ++dx)
                m0 = fmaxf(m0, p0[(4 * h + dy) * 160 + 4 * w + dx]);
        const float* p1 = x1 + bc * 6400;
        float m1 = -INFINITY;
#pragma unroll
        for (int dy = 0; dy < 2; ++dy)
#pragma unroll
            for (int dx = 0; dx < 2; ++dx)
                m1 = fmaxf(m1, p1[(2 * h + dy) * 80 + 2 * w + dx]);
        float v2 = x2[bc * GP + pix];
        float v3 = x3[bc * 400 + (h / 2) * 20 + (w / 2)];
        float v4 = x4[bc * 100 + (h / 4) * 10 + (w / 4)];
        tile[ly + r][lx] = (m0 + m1 + v2 + v3 + v4) * 0.2f;
    }
    __syncthreads();
#pragma unroll
    for (int r = 0; r < 64; r += 4) {
        int p = ly + r;
        fe_pm[((size_t)b * GP + pix0 + p) * C_ + c0 + lx] = tile[lx][p];
    }
}

// ---- weight permute+convert (both weights in one launch) ------------------------
__global__ void wcvt_kernel(const float* __restrict__ wA, const float* __restrict__ wB,
                            ushort* __restrict__ oA, ushort* __restrict__ oB) {
    const float* w = blockIdx.y ? wB : wA;
    ushort* out = blockIdx.y ? oB : oA;
    int idx = blockIdx.x * 256 + threadIdx.x;   // 256*2304
    int o = idx / KDIM;
    int rem = idx - o * KDIM;
    int c = rem / 9, t = rem - c * 9;
    out[(size_t)o * KDIM + t * 256 + c] = f2b(w[idx]);
}

// ---- im2col (3x3 pad1 on fe_pm) -> A1[b*1600+pix][t*256+c] bf16 -----------------
__global__ void im2col_kernel(const float* __restrict__ fe_pm, ushort* __restrict__ A1) {
    int pix = blockIdx.x % GP, b = blockIdx.x / GP;
    int c = threadIdx.x;
    const float* fb = fe_pm + (size_t)b * GP * C_;
    ushort* dst = A1 + (size_t)blockIdx.x * KDIM;
    int h = pix / GW, w = pix - (pix / GW) * GW;
#pragma unroll
    for (int t = 0; t < 9; ++t) {
        int y = h + t / 3 - 1, x = w + t % 3 - 1;
        float v = (y >= 0 && y < GH && x >= 0 && x < GW) ? fb[(size_t)(y * GW + x) * C_ + c]
                                                         : 0.f;
        dst[t * 256 + c] = f2b(v);
    }
}

// ---- bilinear sampling (fe_pm) -> S[b*1600+pix][t*256+c] bf16 -------------------
__global__ void sample_kernel(const float* __restrict__ fe_pm, const float* __restrict__ pts,
                              ushort* __restrict__ S) {
    int pix = blockIdx.x % GP, b = blockIdx.x / GP;
    int c = threadIdx.x;
    const float* fb = fe_pm + (size_t)b * GP * C_;
    const float* pb = pts + (size_t)b * 18 * GP + pix;
    ushort* dst = S + (size_t)blockIdx.x * KDIM;
    int h = pix / GW, w = pix - (pix / GW) * GW;
#pragma unroll
    for (int t = 0; t < 9; ++t) {
        float py = (float)h + pb[(2 * t) * GP];
        float px = (float)w + pb[(2 * t + 1) * GP];
        float y0f = floorf(py), x0f = floorf(px);
        int y0 = (int)y0f, x0 = (int)x0f;
        float wy1 = py - y0f, wx1 = px - x0f;
        float wy0 = 1.f - wy1, wx0 = 1.f - wx1;
        auto tap = [&](int yy, int xx) -> float {
            return (yy >= 0 && yy < GH && xx >= 0 && xx < GW)
                       ? fb[(size_t)(yy * GW + xx) * C_ + c]
                       : 0.f;
        };
        float v = tap(y0, x0) * wy0 * wx0 + tap(y0, x0 + 1) * wy0 * wx1 +
                  tap(y0 + 1, x0) * wy1 * wx0 + tap(y0 + 1, x0 + 1) * wy1 * wx1;
        dst[t * 256 + c] = f2b(v);
    }
}

// ---- bf16 MFMA GEMM, pure-copy staging, depth-2 prefetch, dbuf LDS --------------
// A: [6400][2304] bf16 (k-contiguous); W: [256][2304] bf16.
// Two register sets (X,Y): loads for chunk k+2 issued a full chunk before their
// ds_write -> counted vmcnt finds them complete; latency amortized over 2 phases.
__global__ __launch_bounds__(256) void mfma_gemm(const ushort* __restrict__ A,
                                                 const ushort* __restrict__ Bw,
                                                 const float* __restrict__ bias,
                                                 float* __restrict__ Cout) {
    __shared__ ushort As[2][64 * 64];
    __shared__ ushort Bs[2][64 * 64];
    int tid = threadIdx.x;
    int lane = tid & 63;
    int wid = tid >> 6;
    int wm = wid >> 1, wn = wid & 1;
    int m0 = blockIdx.x * 64;
    int n0 = blockIdx.y * 64;

    int sr = tid >> 3;                  // staging row 0..31 (and +32)
    int ss = tid & 7;                   // logical 16B slot 0..7
    int wsl = (ss ^ (sr & 7)) * 8;      // swizzled short offset within row
    const ushort* gA0 = A + (size_t)(m0 + sr) * KDIM + ss * 8;
    const ushort* gA1 = A + (size_t)(m0 + sr + 32) * KDIM + ss * 8;
    const ushort* gB0 = Bw + (size_t)(n0 + sr) * KDIM + ss * 8;
    const ushort* gB1 = Bw + (size_t)(n0 + sr + 32) * KDIM + ss * 8;

    f32x4 acc[2][2];
#pragma unroll
    for (int i = 0; i < 2; ++i)
#pragma unroll
        for (int j = 0; j < 2; ++j) acc[i][j] = (f32x4){0.f, 0.f, 0.f, 0.f};

    short8b xA0, xA1, xB0, xB1;   // register set X
    short8b yA0, yA1, yB0, yB1;   // register set Y

    auto loadX = [&]() {
        xA0 = *(const short8b*)gA0; xA1 = *(const short8b*)gA1;
        xB0 = *(const short8b*)gB0; xB1 = *(const short8b*)gB1;
        gA0 += 64; gA1 += 64; gB0 += 64; gB1 += 64;
    };
    auto loadY = [&]() {
        yA0 = *(const short8b*)gA0; yA1 = *(const short8b*)gA1;
        yB0 = *(const short8b*)gB0; yB1 = *(const short8b*)gB1;
        gA0 += 64; gA1 += 64; gB0 += 64; gB1 += 64;
    };
    auto writeL = [&](int buf, short8b a0, short8b a1, short8b b0, short8b b1) {
        *(short8b*)(As[buf] + sr * 64 + wsl) = a0;
        *(short8b*)(As[buf] + (sr + 32) * 64 + wsl) = a1;
        *(short8b*)(Bs[buf] + sr * 64 + wsl) = b0;
        *(short8b*)(Bs[buf] + (sr + 32) * 64 + wsl) = b1;
    };
    auto compute = [&](int cur) {
#pragma unroll
        for (int kq = 0; kq < 2; ++kq) {
            int k16 = kq * 4 + (lane >> 4);
            short8b af[2], bfr[2];
#pragma unroll
            for (int i = 0; i < 2; ++i) {
                int rA = wm * 32 + i * 16 + (lane & 15);
                af[i] = *(const short8b*)(As[cur] + rA * 64 + ((k16 ^ (rA & 7)) * 8));
                int rB = wn * 32 + i * 16 + (lane & 15);
                bfr[i] = *(const short8b*)(Bs[cur] + rB * 64 + ((k16 ^ (rB & 7)) * 8));
            }
#pragma unroll
            for (int in = 0; in < 2; ++in)
#pragma unroll
                for (int im = 0; im < 2; ++im)
                    acc[in][im] = __builtin_amdgcn_mfma_f32_16x16x32_bf16(
                        bfr[in], af[im], acc[in][im], 0, 0, 0);
        }
    };

    constexpr int NCH = KDIM / 64;   // 36 chunks (even)
    loadX();                          // chunk 0
    loadY();                          // chunk 1
    writeL(0, xA0, xA1, xB0, xB1);
    __syncthreads();

    for (int kc = 0; kc < NCH; kc += 2) {
        // phase A: compute chunk kc (LDS[0]); Y holds kc+1; prefetch kc+2 into X
        if (kc + 2 < NCH) loadX();
        compute(0);
        writeL(1, yA0, yA1, yB0, yB1);     // waits Y (issued one phase-pair ago)
        __syncthreads();
        // phase B: compute chunk kc+1 (LDS[1]); X holds kc+2; prefetch kc+3 into Y
        if (kc + 3 < NCH) loadY();
        compute(1);
        if (kc + 2 < NCH) writeL(0, xA0, xA1, xB0, xB1);
        __syncthreads();
    }

    int b = m0 / GP;
    int pix0 = m0 - b * GP;     // 1600 % 64 == 0 -> tile never crosses batch
    float* Cb = Cout + (size_t)b * C_ * GP;
#pragma unroll
    for (int in = 0; in < 2; ++in) {
#pragma unroll
        for (int r = 0; r < 4; ++r) {
            int n = n0 + wn * 32 + in * 16 + (lane >> 4) * 4 + r;
            float bv = bias ? bias[n] : 0.f;
#pragma unroll
            for (int im = 0; im < 2; ++im) {
                int m = pix0 + wm * 32 + im * 16 + (lane & 15);
                Cb[(size_t)n * GP + m] = fmaxf(acc[in][im][r] + bv, 0.f);
            }
        }
    }
}

// ---- pts = conv1x1(p1, w_pts_out) + b -------------------------------------------
__global__ void pts_kernel(const float* __restrict__ p1, const float* __restrict__ wpo,
                           const float* __restrict__ bpo, float* __restrict__ pts) {
    int idx = blockIdx.x * 256 + threadIdx.x;   // over B*18*1600
    int pix = idx % GP;
    int p = (idx / GP) % 18;
    int b = idx / (GP * 18);
    const float* pb = p1 + (size_t)b * C_ * GP + pix;
    const float* wp = wpo + p * C_;
    float s = bpo[p];
    for (int c = 0; c < C_; ++c) s += pb[(size_t)c * GP] * wp[c];
    pts[idx] = s;
}

// ---- per-level tables ------------------------------------------------------------
__device__ constexpr int L_S[5] = {160, 80, 40, 20, 10};
__device__ constexpr int L_NPX[5] = {102400, 25600, 6400, 1600, 400};
__device__ constexpr int YK_START[5] = {0, 400, 500, 525, 532};      // 534 blocks total
__device__ constexpr int FC_START[5] = {0, 1600, 2000, 2100, 2125};  // 2132 blocks total
__device__ constexpr size_t L_YBASE[5] = {0, 7372800, 9216000, 9676800, 9792000};
__device__ constexpr size_t L_OUT[5] = {0, 26214400, 32768000, 34406400, 34816000};

__device__ inline int lvl_of(int bx, const int* start) {
    return (bx >= start[4]) ? 4 : (bx >= start[3]) ? 3 : (bx >= start[2]) ? 2
           : (bx >= start[1]) ? 1 : 0;
}

// ---- att pass 1 (ALL levels): y[g][conv*9+t][bp] = sum_{c in grp} w[c,t]*x[c,bp] --
__global__ __launch_bounds__(256) void yk_all(const float* __restrict__ x0,
                                              const float* __restrict__ x1,
                                              const float* __restrict__ x2,
                                              const float* __restrict__ x3,
                                              const float* __restrict__ x4,
                                              const float* __restrict__ w_red1,
                                              const float* __restrict__ w_red2,
                                              ushort* __restrict__ y_all) {
    int bx = blockIdx.x;
    int lvl = lvl_of(bx, YK_START);
    const float* x = lvl == 0 ? x0 : lvl == 1 ? x1 : lvl == 2 ? x2 : lvl == 3 ? x3 : x4;
    int s = L_S[lvl];
    int npx = L_NPX[lvl];
    int bp = (bx - YK_START[lvl]) * 256 + threadIdx.x;
    int g = blockIdx.y;
    if (bp >= npx) return;
    int ss_ = s * s;
    int b = bp / ss_;
    int p = bp - b * ss_;
    const float* xg = x + ((size_t)b * C_ + g * 64) * ss_ + p;
    const float* w1g = w_red1 + (size_t)lvl * KDIM + g * 64 * 9;
    const float* w2g = w_red2 + (size_t)lvl * KDIM + g * 64 * 9;
    float a1[9] = {}, a2[9] = {};
#pragma unroll 4
    for (int ci = 0; ci < 64; ++ci) {
        float v = xg[(size_t)ci * ss_];
#pragma unroll
        for (int t = 0; t < 9; ++t) {
            a1[t] += w1g[ci * 9 + t] * v;
            a2[t] += w2g[ci * 9 + t] * v;
        }
    }
    ushort* yb = y_all + L_YBASE[lvl] + bp;
#pragma unroll
    for (int t = 0; t < 9; ++t) {
        yb[(size_t)(g * 18 + t) * npx] = f2b(a1[t]);
        yb[(size_t)(g * 18 + 9 + t) * npx] = f2b(a2[t]);
    }
}

// ---- att pass 2 + combine (ALL levels) -------------------------------------------
__global__ __launch_bounds__(256) void fincomb_all(const float* __restrict__ x0,
                                                   const float* __restrict__ x1,
                                                   const float* __restrict__ x2,
                                                   const float* __restrict__ x3,
                                                   const float* __restrict__ x4,
                                                   const ushort* __restrict__ y_all,
                                                   const float* __restrict__ b_red1,
                                                   const float* __restrict__ b_red2,
                                                   const float* __restrict__ bsf,
                                                   float* __restrict__ out) {
    __shared__ float red[2][4][64];
    __shared__ float amap_s[64];
    int bx = blockIdx.x;
    int lvl = lvl_of(bx, FC_START);
    const float* x = lvl == 0 ? x0 : lvl == 1 ? x1 : lvl == 2 ? x2 : lvl == 3 ? x3 : x4;
    int s = L_S[lvl];
    int npx = L_NPX[lvl];
    const ushort* y = y_all + L_YBASE[lvl];
    float* out_l = out + L_OUT[lvl];
    int lane = threadIdx.x & 63;
    int grp = threadIdx.x >> 6;
    int pix_g = (bx - FC_START[lvl]) * 64 + lane;
    bool valid = pix_g < npx;
    int pg = valid ? pix_g : 0;
    int ss_ = s * s;
    int b = pg / ss_;
    int pix = pg - b * ss_;
    int h = pix / s, w = pix - h * s;
    const ushort* yg = y + (size_t)grp * 18 * npx;
    float s1 = 0.f, s2 = 0.f;
#pragma unroll
    for (int t = 0; t < 9; ++t) {
        int dy = t / 3 - 1, dx = t % 3 - 1;
        int hy = h + dy, wx = w + dx;
        if (hy >= 0 && hy < s && wx >= 0 && wx < s) {
            int qq = pg + dy * s + dx;
            s1 += b2f(yg[(size_t)t * npx + qq]);
            s2 += b2f(yg[(size_t)(9 + t) * npx + qq]);
        }
    }
    red[0][grp][lane] = s1;
    red[1][grp][lane] = s2;
    __syncthreads();
    if (grp == 0) {
        float t1 = red[0][0][lane] + red[0][1][lane] + red[0][2][lane] + red[0][3][lane];
        float t2 = red[1][0][lane] + red[1][1][lane] + red[1][2][lane] + red[1][3][lane];
        t1 = tanhf(fmaxf(t1 + b_red1[lvl], 0.f));
        t2 = tanhf(fmaxf(t2 + b_red2[lvl], 0.f));
        amap_s[lane] = t1 + t2;
    }
    __syncthreads();
    if (!valid) return;
    float av = amap_s[lane];
    int gh = h * GH / s, gw = w * GW / s;
    const float* bb = bsf + (size_t)b * C_ * GP + gh * GW + gw;
    const float* xp = x + ((size_t)b * C_ + grp * 64) * ss_ + pix;
    float* op = out_l + ((size_t)b * C_ + grp * 64) * ss_ + pix;
#pragma unroll 4
    for (int ci = 0; ci < 64; ++ci) {
        int c = grp * 64 + ci;
        op[(size_t)ci * ss_] = xp[(size_t)ci * ss_] + bb[(size_t)c * GP] * av;
    }
}

extern "C" void kernel_launch(void* const* d_in, const int* in_sizes, int n_in,
                              void* d_out, int out_size, void* d_ws, size_t ws_size,
                              hipStream_t stream) {
    const float* x[5];
    for (int i = 0; i < 5; ++i) x[i] = (const float*)d_in[i];
    const float* w_red1 = (const float*)d_in[5];
    const float* b_red1 = (const float*)d_in[6];
    const float* w_red2 = (const float*)d_in[7];
    const float* b_red2 = (const float*)d_in[8];
    const float* w_pts_conv = (const float*)d_in[9];
    const float* b_pts_conv = (const float*)d_in[10];
    const float* w_pts_out = (const float*)d_in[11];
    const float* b_pts_out = (const float*)d_in[12];
    const float* w_refine = (const float*)d_in[13];
    float* out = (float*)d_out;

    // workspace layout
    float* ws = (float*)d_ws;
    float* fe_pm = ws;                     // 1,638,400 f32  [b][pix][c]
    float* p1 = fe_pm + 1638400;           // 1,638,400 f32
    float* pts = p1 + 1638400;             //   115,200 f32
    float* bsf = pts + 115200;             // 1,638,400 f32
    ushort* y_all = (ushort*)(bsf + 1638400);      // 9,820,800 bf16 (all levels)
    ushort* AS_buf = y_all + 9820800;              // 14,745,600 bf16 (A1, then S)
    ushort* Wb1 = AS_buf + (size_t)MT * KDIM;      //   589,824 bf16
    ushort* Wb2 = Wb1 + (size_t)C_ * KDIM;         //   589,824 bf16
    // total ~71.4 MB

    fe_kernel<<<dim3(25, 4, B_), 256, 0, stream>>>(x[0], x[1], x[2], x[3], x[4], fe_pm);
    wcvt_kernel<<<dim3(2304, 2), 256, 0, stream>>>(w_pts_conv, w_refine, Wb1, Wb2);
    im2col_kernel<<<MT, 256, 0, stream>>>(fe_pm, AS_buf);
    mfma_gemm<<<dim3(100, 4), 256, 0, stream>>>(AS_buf, Wb1, b_pts_conv, p1);
    pts_kernel<<<450, 256, 0, stream>>>(p1, w_pts_out, b_pts_out, pts);
    sample_kernel<<<MT, 256, 0, stream>>>(fe_pm, pts, AS_buf);   // overwrites A1
    mfma_gemm<<<dim3(100, 4), 256, 0, stream>>>(AS_buf, Wb2, nullptr, bsf);
    yk_all<<<dim3(534, 4), 256, 0, stream>>>(x[0], x[1], x[2], x[3], x[4],
                                             w_red1, w_red2, y_all);
    fincomb_all<<<2132, 256, 0, stream>>>(x[0], x[1], x[2], x[3], x[4], y_all,
                                          b_red1, b_red2, bsf, out);
}